// Round 4
// baseline (1237.311 us; speedup 1.0000x reference)
//
#include <hip/hip_runtime.h>
#include <stdint.h>

#define CAPACITY  65536
#define BATCH     2048
#define KEY_WORDS 32                    // 1024 bits / 32
#define KCHUNK    256                   // keys per scan wave
#define NSPLIT    (CAPACITY / KCHUNK)   // 256 key splits

// ---------------------------------------------------------------------------
// Pack 32 consecutive 0/1 int32s (8 int4s) into one u32. Same packing for
// queries and keys so XOR-popcount distance is exact.
__device__ __forceinline__ uint32_t pack_word(const int4* __restrict__ p) {
    uint32_t word = 0;
#pragma unroll
    for (int j = 0; j < 8; ++j) {
        int4 v = p[j];
        word |= (uint32_t)(v.x & 1) << (4 * j + 0);
        word |= (uint32_t)(v.y & 1) << (4 * j + 1);
        word |= (uint32_t)(v.z & 1) << (4 * j + 2);
        word |= (uint32_t)(v.w & 1) << (4 * j + 3);
    }
    return word;
}

// Row-major pack: out[row][word]. Used for both queries and keys.
__global__ void pack_bits_kernel(const int* __restrict__ in,
                                 uint32_t* __restrict__ out, int nwords) {
    int w = blockIdx.x * blockDim.x + threadIdx.x;
    if (w >= nwords) return;
    out[w] = pack_word(reinterpret_cast<const int4*>(in) + (size_t)w * 8);
}

// best[] must be re-initialized every call (harness poisons ws once, then replays).
__global__ void init_best_kernel(uint32_t* __restrict__ best) {
    best[blockIdx.x * 256 + threadIdx.x] = 0xFFFFFFFFu;
}

// ---------------------------------------------------------------------------
// Scan, lane = query. Each wave owns 64 queries (one per lane, 32 VGPRs of
// query words each) and scans KCHUNK keys. Key words are wave-uniform loads
// (address depends only on blockIdx + loop var) -> s_load into SGPRs via the
// scalar/constant cache: vector-memory key traffic per pair drops 32x vs the
// lane=key layout. Inner loop is pure v_xor(s,v) + v_bcnt. No LDS, no
// barriers. Winner merge: atomicMin over packed (dist<<16)|key, which equals
// the reference's first-max argmax (min dist, tie -> min index).
__launch_bounds__(256, 8)
__global__ void scan_kernel(const uint32_t* __restrict__ qpack,
                            const uint32_t* __restrict__ kpack,
                            uint32_t* __restrict__ best) {
    const int t      = threadIdx.x;
    const int lane   = t & 63;
    const int wid    = t >> 6;              // 4 waves = 4 query groups
    const int qgb    = blockIdx.x & 7;      // 8 block classes x 4 = 32 qgroups
    const int ksplit = blockIdx.x >> 3;
    const int query  = (qgb * 4 + wid) * 64 + lane;

    // one query per lane: 32 words = 32 VGPRs
    uint32_t q[KEY_WORDS];
    const uint4* qp4 = reinterpret_cast<const uint4*>(qpack + (size_t)query * KEY_WORDS);
#pragma unroll
    for (int j = 0; j < 8; ++j) {
        uint4 v = qp4[j];
        q[4 * j + 0] = v.x; q[4 * j + 1] = v.y;
        q[4 * j + 2] = v.z; q[4 * j + 3] = v.w;
    }

    uint32_t b = 0xFFFFFFFFu;
    const int k0 = ksplit * KCHUNK;
#pragma unroll 2
    for (int k = k0; k < k0 + KCHUNK; ++k) {
        const uint4* kw4 = reinterpret_cast<const uint4*>(kpack + (size_t)k * KEY_WORDS);
        uint32_t dist = 0;
#pragma unroll
        for (int j = 0; j < 8; ++j) {
            uint4 kv = kw4[j];               // wave-uniform -> SGPR (s_load)
            dist += __popc(kv.x ^ q[4 * j + 0]);
            dist += __popc(kv.y ^ q[4 * j + 1]);
            dist += __popc(kv.z ^ q[4 * j + 2]);
            dist += __popc(kv.w ^ q[4 * j + 3]);
        }
        b = min(b, (dist << 16) | (uint32_t)k);
    }
    atomicMin(&best[query], b);              // device-scope, order-independent
}

// ---------------------------------------------------------------------------
// Finalize: best[q] -> gather values row (1024 f32).
__global__ void finalize_kernel(const uint32_t* __restrict__ best,
                                const float* __restrict__ values,
                                float* __restrict__ out) {
    const int qy  = blockIdx.x;
    const int idx = (int)(best[qy] & 0xFFFFu);
    const float4* v4 = reinterpret_cast<const float4*>(values) + (size_t)idx * 256;
    float4* o4 = reinterpret_cast<float4*>(out) + (size_t)qy * 256;
    o4[threadIdx.x] = v4[threadIdx.x];
}

// ---------------------------------------------------------------------------
extern "C" void kernel_launch(void* const* d_in, const int* in_sizes, int n_in,
                              void* d_out, int out_size, void* d_ws, size_t ws_size,
                              hipStream_t stream) {
    const int*   query  = (const int*)d_in[0];   // [2048, 1024] int32 0/1
    const int*   keys   = (const int*)d_in[1];   // [65536, 1024] int32 0/1
    const float* values = (const float*)d_in[2]; // [65536, 1024] f32
    float*       out    = (float*)d_out;         // [2048, 1024] f32

    char* ws = (char*)d_ws;
    uint32_t* qpack = (uint32_t*)ws;                        // 256 KB
    uint32_t* kpack = (uint32_t*)(ws + 262144);             // 8 MB
    uint32_t* best  = (uint32_t*)(ws + 262144 + 8388608);   // 8 KB

    init_best_kernel<<<BATCH / 256, 256, 0, stream>>>(best);
    pack_bits_kernel<<<BATCH * KEY_WORDS / 256, 256, 0, stream>>>(
        query, qpack, BATCH * KEY_WORDS);
    pack_bits_kernel<<<CAPACITY * KEY_WORDS / 256, 256, 0, stream>>>(
        keys, kpack, CAPACITY * KEY_WORDS);

    // 8 block classes (32 qgroups) x 256 ksplits = 2048 blocks x 4 waves
    scan_kernel<<<8 * NSPLIT, 256, 0, stream>>>(qpack, kpack, best);

    finalize_kernel<<<BATCH, 256, 0, stream>>>(best, values, out);
}

// Round 5
// 401.088 us; speedup vs baseline: 3.0849x; 3.0849x over previous
//
#include <hip/hip_runtime.h>
#include <stdint.h>

#define CAPACITY  65536
#define BATCH     2048
#define KEY_WORDS 32                    // 1024 bits / 32
#define KCHUNK    256                   // keys per scan block (32 KB chunk)
#define NSPLIT    (CAPACITY / KCHUNK)   // 256 key splits

// ---------------------------------------------------------------------------
// Pack 32 consecutive 0/1 int32s (8 int4s) into one u32. Same packing for
// queries and keys so XOR-popcount distance is exact.
__device__ __forceinline__ uint32_t pack_word(const int4* __restrict__ p) {
    uint32_t word = 0;
#pragma unroll
    for (int j = 0; j < 8; ++j) {
        int4 v = p[j];
        word |= (uint32_t)(v.x & 1) << (4 * j + 0);
        word |= (uint32_t)(v.y & 1) << (4 * j + 1);
        word |= (uint32_t)(v.z & 1) << (4 * j + 2);
        word |= (uint32_t)(v.w & 1) << (4 * j + 3);
    }
    return word;
}

// Row-major pack: out[row][word]. Used for both queries and keys.
__global__ void pack_bits_kernel(const int* __restrict__ in,
                                 uint32_t* __restrict__ out, int nwords) {
    int w = blockIdx.x * blockDim.x + threadIdx.x;
    if (w >= nwords) return;
    out[w] = pack_word(reinterpret_cast<const int4*>(in) + (size_t)w * 8);
}

// best[] must be re-initialized every call (harness poisons ws once, replays).
__global__ void init_best_kernel(uint32_t* __restrict__ best) {
    best[blockIdx.x * 256 + threadIdx.x] = 0xFFFFFFFFu;
}

// ---------------------------------------------------------------------------
// Scan, lane = query. Each wave owns 64 queries (one per lane, 32 VGPRs of
// query words) and scans a 256-key / 32 KB chunk. Key-word loads are wave-
// uniform (broadcast) -> one 16B transaction per load serving 64 pairs:
// key traffic is 2 B/pair instead of round-3's 64 B/pair.
//
// launch_bounds(256,4): VGPR cap 128. Demand ~106 (q:32 + kv in flight with
// unroll 2: ~64 + misc). (256,8) capped at 64 and spilled q -> 130 MB scratch
// writes + 3.9 GB fetch in round 4.
//
// Block order: ksplit = low bits => XCD = blockIdx%8 = ksplit%8, so each key
// chunk is resident on exactly ONE XCD's L2 (1 MB/XCD total). Round 4's
// (qgb low) ordering streamed all 256 chunks through every L2 (6.6 MB > 4 MB).
//
// Winner merge: atomicMin over packed (dist<<16)|key == reference first-max.
__launch_bounds__(256, 4)
__global__ void scan_kernel(const uint32_t* __restrict__ qpack,
                            const uint32_t* __restrict__ kpack,
                            uint32_t* __restrict__ best) {
    const int t      = threadIdx.x;
    const int lane   = t & 63;
    const int wid    = t >> 6;                   // 4 waves = 4 query subgroups
    const int ksplit = blockIdx.x & (NSPLIT - 1);
    const int qgb    = blockIdx.x >> 8;          // 8 query groups of 256
    const int query  = qgb * 256 + wid * 64 + lane;

    // one query per lane: 32 words = 32 VGPRs
    uint32_t q[KEY_WORDS];
    const uint4* qp4 = reinterpret_cast<const uint4*>(qpack + (size_t)query * KEY_WORDS);
#pragma unroll
    for (int j = 0; j < 8; ++j) {
        uint4 v = qp4[j];
        q[4 * j + 0] = v.x; q[4 * j + 1] = v.y;
        q[4 * j + 2] = v.z; q[4 * j + 3] = v.w;
    }

    uint32_t b = 0xFFFFFFFFu;
    const int k0 = ksplit * KCHUNK;
#pragma unroll 2
    for (int k = k0; k < k0 + KCHUNK; ++k) {
        const uint4* kw4 = reinterpret_cast<const uint4*>(kpack + (size_t)k * KEY_WORDS);
        uint32_t dist = 0;
#pragma unroll
        for (int j = 0; j < 8; ++j) {
            uint4 kv = kw4[j];               // wave-uniform broadcast load
            dist += __popc(kv.x ^ q[4 * j + 0]);
            dist += __popc(kv.y ^ q[4 * j + 1]);
            dist += __popc(kv.z ^ q[4 * j + 2]);
            dist += __popc(kv.w ^ q[4 * j + 3]);
        }
        b = min(b, (dist << 16) | (uint32_t)k);
    }
    atomicMin(&best[query], b);              // device-scope, order-independent
}

// ---------------------------------------------------------------------------
// Finalize: best[q] -> gather values row (1024 f32).
__global__ void finalize_kernel(const uint32_t* __restrict__ best,
                                const float* __restrict__ values,
                                float* __restrict__ out) {
    const int qy  = blockIdx.x;
    const int idx = (int)(best[qy] & 0xFFFFu);
    const float4* v4 = reinterpret_cast<const float4*>(values) + (size_t)idx * 256;
    float4* o4 = reinterpret_cast<float4*>(out) + (size_t)qy * 256;
    o4[threadIdx.x] = v4[threadIdx.x];
}

// ---------------------------------------------------------------------------
extern "C" void kernel_launch(void* const* d_in, const int* in_sizes, int n_in,
                              void* d_out, int out_size, void* d_ws, size_t ws_size,
                              hipStream_t stream) {
    const int*   query  = (const int*)d_in[0];   // [2048, 1024] int32 0/1
    const int*   keys   = (const int*)d_in[1];   // [65536, 1024] int32 0/1
    const float* values = (const float*)d_in[2]; // [65536, 1024] f32
    float*       out    = (float*)d_out;         // [2048, 1024] f32

    char* ws = (char*)d_ws;
    uint32_t* qpack = (uint32_t*)ws;                        // 256 KB
    uint32_t* kpack = (uint32_t*)(ws + 262144);             // 8 MB
    uint32_t* best  = (uint32_t*)(ws + 262144 + 8388608);   // 8 KB

    init_best_kernel<<<BATCH / 256, 256, 0, stream>>>(best);
    pack_bits_kernel<<<BATCH * KEY_WORDS / 256, 256, 0, stream>>>(
        query, qpack, BATCH * KEY_WORDS);
    pack_bits_kernel<<<CAPACITY * KEY_WORDS / 256, 256, 0, stream>>>(
        keys, kpack, CAPACITY * KEY_WORDS);

    // 8 query groups x 256 ksplits; ksplit in low bits -> chunk pinned to XCD
    scan_kernel<<<8 * NSPLIT, 256, 0, stream>>>(qpack, kpack, best);

    finalize_kernel<<<BATCH, 256, 0, stream>>>(best, values, out);
}